// Round 9
// baseline (412.229 us; speedup 1.0000x reference)
//
#include <hip/hip_runtime.h>
#include <hip/hip_bf16.h>

#define DIMN 128
#define LN_EPS 1e-5f
#define WPAD 136   // padded row length in bf16 (272 B = 17*16, keeps b128 aligned, ~2-way banks)
#define LOG2E 1.4426950408889634f

typedef __bf16 bf16x8 __attribute__((ext_vector_type(8)));
typedef float f32x4 __attribute__((ext_vector_type(4)));

__device__ __forceinline__ float bf_even(uint32_t u) {  // element at even dim (low 16 bits)
    union { uint32_t u; float f; } c; c.u = u << 16; return c.f;
}
// element at odd dim (high 16 bits) -- mask-free: low-16 garbage is <=2^-8
// relative noise (below the bf16 rounding already present), saves the AND.
__device__ __forceinline__ float bf_odd(uint32_t u) {
    union { uint32_t u; float f; } c; c.u = u; return c.f;
}

// ---------------- K1: W split (blocks 0..255) + hist/rank (rest) ----------------
__global__ __launch_bounds__(256) void k_prep(
        const float* __restrict__ Wq, const float* __restrict__ Wk,
        const float* __restrict__ Wv, const float* __restrict__ Wp,
        __bf16* __restrict__ wsplit, const int* __restrict__ qidx,
        int* __restrict__ counts, int* __restrict__ rank, int E) {
    int bi = blockIdx.x;
    if (bi < 256) {
        int w = bi >> 6;
        const float* W = (w == 0) ? Wq : (w == 1) ? Wk : (w == 2) ? Wv : Wp;
        __bf16* hi = wsplit + (size_t)w * 32768;
        __bf16* lo = hi + 16384;
        int i = (bi & 63) * 256 + threadIdx.x;
        float x = W[i];
        __bf16 h = (__bf16)x;
        hi[i] = h;
        lo[i] = (__bf16)(x - (float)h);
    } else {
        int i = (bi - 256) * 256 + threadIdx.x;
        if (i < E) rank[i] = atomicAdd(&counts[qidx[i]], 1);
    }
}

// ---------------- K2: LDS-W projections (+ scan1 in low blocks) ----------------
// chunk sized so grid <= 512 blocks (2/CU, one scheduling round): each block
// stages W into LDS once (vs 1875x at chunk=5) and amortizes over ~19 tiles.
__global__ __launch_bounds__(256, 2) void k_proj3(
        const float* __restrict__ query, const float* __restrict__ keys,
        const float* __restrict__ values, const __bf16* __restrict__ wsplit,
        const float* __restrict__ bq, const float* __restrict__ bk,
        const float* __restrict__ bv, float* __restrict__ Qp,
        __bf16* __restrict__ KV, int NQ_, int NK_,
        const int* __restrict__ counts, int* __restrict__ offs,
        int* __restrict__ bsum, int nb, int chunk) {
    __shared__ int s[256];
    __shared__ __align__(16) __bf16 WH[128 * WPAD];
    __shared__ __align__(16) __bf16 WL[128 * WPAD];

    // ---- scan1 piggyback (counts ready: k_prep ran before) ----
    if ((int)blockIdx.x < nb) {
        int t = threadIdx.x;
        int i = blockIdx.x * 256 + t;
        int v = (i < NQ_) ? counts[i] : 0;
        s[t] = v;
        __syncthreads();
        for (int o = 1; o < 256; o <<= 1) {
            int x = (t >= o) ? s[t - o] : 0;
            __syncthreads();
            s[t] += x;
            __syncthreads();
        }
        if (i < NQ_) offs[i] = s[t] - v;
        if (t == 255) bsum[blockIdx.x] = s[t];
    }

    int lane = threadIdx.x & 63;
    int wid  = threadIdx.x >> 6;
    int r = lane & 15, g = lane >> 4;
    int rowoff = (wid >> 1) * 16;   // 0 or 16 within the 32-row tile
    int chalf  = wid & 1;           // column half: cols [chalf*64, chalf*64+64)

    int ntq = (NQ_ + 31) >> 5;
    int ntk = (NK_ + 31) >> 5;
    int total = ntq + 2 * ntk;

    int t0 = blockIdx.x * chunk;
    int t1 = t0 + chunk; if (t1 > total) t1 = total;
    int staged = -1;
    float bias_n[4];

    for (int t = t0; t < t1; ++t) {
        int m, tt;
        if (t < ntq)            { m = 0; tt = t; }
        else if (t < ntq + ntk) { m = 1; tt = t - ntq; }
        else                    { m = 2; tt = t - ntq - ntk; }

        if (m != staged) {
            if (staged != -1) __syncthreads();   // drain readers of old W
            const uint4* srcH = (const uint4*)(wsplit + (size_t)m * 32768);
#pragma unroll
            for (int it = 0; it < 8; ++it) {
                int cid = threadIdx.x + it * 256;     // 2048 16B-chunks per plane
                int n = cid >> 4, c16 = cid & 15;
                *(uint4*)((char*)WH + n * (WPAD * 2) + c16 * 16) = srcH[cid];
            }
            if (m == 0) {                             // WL only needed for 3-pass Q
                const uint4* srcL = (const uint4*)(wsplit + (size_t)m * 32768 + 16384);
#pragma unroll
                for (int it = 0; it < 8; ++it) {
                    int cid = threadIdx.x + it * 256;
                    int n = cid >> 4, c16 = cid & 15;
                    *(uint4*)((char*)WL + n * (WPAD * 2) + c16 * 16) = srcL[cid];
                }
            }
            __syncthreads();
            staged = m;
            const float* bias = (m == 0) ? bq : (m == 1) ? bk : bv;
#pragma unroll
            for (int c = 0; c < 4; ++c) bias_n[c] = bias[(chalf * 4 + c) * 16 + r];
        }

        const float* X = (m == 0) ? query : (m == 1) ? keys : values;
        int M = (m == 0) ? NQ_ : NK_;
        int rb = tt * 32 + rowoff;
        int arow = rb + r; if (arow >= M) arow = M - 1;
        const float* xrow = X + (size_t)arow * DIMN;

        bf16x8 Ah[4], Al[4];
#pragma unroll
        for (int ks = 0; ks < 4; ++ks) {
            const float* px = xrow + ks * 32 + g * 8;
            f32x4 v0 = *(const f32x4*)(px);
            f32x4 v1 = *(const f32x4*)(px + 4);
#pragma unroll
            for (int i = 0; i < 4; ++i) {
                __bf16 h0 = (__bf16)v0[i];
                __bf16 h1 = (__bf16)v1[i];
                Ah[ks][i]     = h0;
                Ah[ks][i + 4] = h1;
                if (m == 0) {
                    Al[ks][i]     = (__bf16)(v0[i] - (float)h0);
                    Al[ks][i + 4] = (__bf16)(v1[i] - (float)h1);
                }
            }
        }

        f32x4 acc[4];
#pragma unroll
        for (int c = 0; c < 4; ++c) {
            acc[c] = (f32x4){0.f, 0.f, 0.f, 0.f};
            int n = (chalf * 4 + c) * 16 + r;
#pragma unroll
            for (int ks = 0; ks < 4; ++ks) {
                bf16x8 Bh = *(const bf16x8*)(WH + n * WPAD + ks * 32 + g * 8);
                acc[c] = __builtin_amdgcn_mfma_f32_16x16x32_bf16(Ah[ks], Bh, acc[c], 0, 0, 0);
                if (m == 0) {
                    bf16x8 Bl = *(const bf16x8*)(WL + n * WPAD + ks * 32 + g * 8);
                    acc[c] = __builtin_amdgcn_mfma_f32_16x16x32_bf16(Ah[ks], Bl, acc[c], 0, 0, 0);
                    acc[c] = __builtin_amdgcn_mfma_f32_16x16x32_bf16(Al[ks], Bh, acc[c], 0, 0, 0);
                }
            }
        }

        if (m == 0) {
#pragma unroll
            for (int c = 0; c < 4; ++c) {
                int n = (chalf * 4 + c) * 16 + r;
#pragma unroll
                for (int i = 0; i < 4; ++i) {
                    int row = rb + g * 4 + i;
                    if (row < M) Qp[(size_t)row * DIMN + n] = acc[c][i] + bias_n[c];
                }
            }
        } else {
            int vofs = (m == 2) ? 128 : 0;
#pragma unroll
            for (int c = 0; c < 4; ++c) {
                int n = (chalf * 4 + c) * 16 + r;
#pragma unroll
                for (int i = 0; i < 4; ++i) {
                    int row = rb + g * 4 + i;
                    if (row < M) KV[(size_t)row * 256 + vofs + n] = (__bf16)(acc[c][i] + bias_n[c]);
                }
            }
        }
    }
}

__global__ __launch_bounds__(1024) void k_scan2(int* __restrict__ bsum, int nb) {
    __shared__ int s[1024];
    int t = threadIdx.x;
    int v = (t < nb) ? bsum[t] : 0;
    s[t] = v;
    __syncthreads();
    for (int o = 1; o < 1024; o <<= 1) {
        int x = (t >= o) ? s[t - o] : 0;
        __syncthreads();
        s[t] += x;
        __syncthreads();
    }
    if (t < nb) bsum[t] = s[t];  // inclusive block-sum scan
}

// final offset of query i = offs[i] + (i>=256 ? bsum[i/256-1] : 0)
__global__ void k_scatter(const int* __restrict__ qidx, const int* __restrict__ kidx,
                          const int* __restrict__ offs, const int* __restrict__ bsum,
                          const int* __restrict__ rank, int* __restrict__ skey, int E) {
    int i = blockIdx.x * 256 + threadIdx.x;
    if (i < E) {
        int q = qidx[i];
        int base = offs[q] + ((q >= 256) ? bsum[(q >> 8) - 1] : 0);
        skey[base + rank[i]] = kidx[i];
    }
}

// ---------------- per-query softmax aggregation ----------------
// 4 edges per wave (16 lanes / edge, 8 dims / lane), x3 batched: 12 edges and
// 6 independent dwordx4 KV gathers in flight per wave iteration.
__device__ __forceinline__ float score8(uint4 ku, const f32x4& qa, const f32x4& qb,
                                        const f32x4& aa, const f32x4& ab, float pw) {
    float e, x;
    x = qa[0] + bf_even(ku.x); x = x >= 0.f ? x : pw * x; e  = aa[0] * x;
    x = qa[1] + bf_odd (ku.x); x = x >= 0.f ? x : pw * x; e += aa[1] * x;
    x = qa[2] + bf_even(ku.y); x = x >= 0.f ? x : pw * x; e += aa[2] * x;
    x = qa[3] + bf_odd (ku.y); x = x >= 0.f ? x : pw * x; e += aa[3] * x;
    x = qb[0] + bf_even(ku.z); x = x >= 0.f ? x : pw * x; e += ab[0] * x;
    x = qb[1] + bf_odd (ku.z); x = x >= 0.f ? x : pw * x; e += ab[1] * x;
    x = qb[2] + bf_even(ku.w); x = x >= 0.f ? x : pw * x; e += ab[2] * x;
    x = qb[3] + bf_odd (ku.w); x = x >= 0.f ? x : pw * x; e += ab[3] * x;
    return e;
}

__device__ __forceinline__ void acc8(uint4 vu, float w, f32x4& c0, f32x4& c1) {
    c0[0] += w * bf_even(vu.x); c0[1] += w * bf_odd(vu.x);
    c0[2] += w * bf_even(vu.y); c0[3] += w * bf_odd(vu.y);
    c1[0] += w * bf_even(vu.z); c1[1] += w * bf_odd(vu.z);
    c1[2] += w * bf_even(vu.w); c1[3] += w * bf_odd(vu.w);
}

__device__ __forceinline__ float red1(float v) {   // += partner lane (xor 1)
    return v + __int_as_float(__builtin_amdgcn_ds_swizzle(__float_as_int(v), 0x041F));
}
__device__ __forceinline__ float redg(float v) {   // += across the 4 edge groups
    v += __int_as_float(__builtin_amdgcn_ds_swizzle(__float_as_int(v), 0x401F)); // xor16
    v += __shfl_xor(v, 32, 64);                                                  // xor32
    return v;
}

__global__ __launch_bounds__(256) void k_attn(
        const float* __restrict__ Qp, const __bf16* __restrict__ KV,
        const int* __restrict__ offs, const int* __restrict__ bsum,
        const int* __restrict__ skey, const float* __restrict__ a,
        const float* __restrict__ prelu_w, float* __restrict__ msg,
        int NQ_, int E_) {
    int lane = threadIdx.x & 63;
    int q = blockIdx.x * 4 + (threadIdx.x >> 6);
    if (q >= NQ_) return;
    int l16 = lane & 15;
    int grp = lane >> 4;
    int d0 = l16 * 8;

    f32x4 aa = *(const f32x4*)(a + d0);
    f32x4 ab = *(const f32x4*)(a + d0 + 4);
#pragma unroll
    for (int i = 0; i < 4; ++i) { aa[i] *= LOG2E; ab[i] *= LOG2E; }  // exp -> exp2
    f32x4 qa = *(const f32x4*)(Qp + (size_t)q * DIMN + d0);
    f32x4 qb = *(const f32x4*)(Qp + (size_t)q * DIMN + d0 + 4);
    float pw = prelu_w[0];

    int beg = offs[q] + ((q >= 256) ? bsum[(q >> 8) - 1] : 0);
    int qn = q + 1;
    int end = (qn == NQ_) ? E_ : offs[qn] + ((qn >= 256) ? bsum[(qn >> 8) - 1] : 0);

    float den = 0.f;
    f32x4 c0 = {0.f, 0.f, 0.f, 0.f}, c1 = {0.f, 0.f, 0.f, 0.f};
    int j = beg;
    for (; j + 12 <= end; j += 12) {        // 12 edges, 6 KV gathers in flight
        int k0 = skey[j + grp];
        int k1 = skey[j + 4 + grp];
        int k2 = skey[j + 8 + grp];
        const uint4* r0 = (const uint4*)(KV + ((size_t)k0 << 8));
        const uint4* r1 = (const uint4*)(KV + ((size_t)k1 << 8));
        const uint4* r2 = (const uint4*)(KV + ((size_t)k2 << 8));
        uint4 ku0 = r0[l16], vu0 = r0[16 + l16];
        uint4 ku1 = r1[l16], vu1 = r1[16 + l16];
        uint4 ku2 = r2[l16], vu2 = r2[16 + l16];
        float e0 = red1(score8(ku0, qa, qb, aa, ab, pw));
        float e1 = red1(score8(ku1, qa, qb, aa, ab, pw));
        float e2 = red1(score8(ku2, qa, qb, aa, ab, pw));
        float w0 = exp2f(e0), w1 = exp2f(e1), w2 = exp2f(e2);
        den += w0 + w1 + w2;
        acc8(vu0, w0, c0, c1);
        acc8(vu1, w1, c0, c1);
        acc8(vu2, w2, c0, c1);
    }
    for (; j < end; j += 4) {               // masked remainder (<=11 edges)
        int jj = j + grp;
        int k = skey[jj < end ? jj : end - 1];
        const uint4* r_ = (const uint4*)(KV + ((size_t)k << 8));
        uint4 ku = r_[l16], vu = r_[16 + l16];
        float e = red1(score8(ku, qa, qb, aa, ab, pw));
        float w = (jj < end) ? exp2f(e) : 0.f;
        den += w;
        acc8(vu, w, c0, c1);
    }

#pragma unroll
    for (int i = 0; i < 4; ++i) { c0[i] = redg(c0[i]); c1[i] = redg(c1[i]); }
    den = redg(den);
    float inv = den > 0.f ? 1.f / den : 0.f;
    if (grp == 0) {
        f32x4 o0, o1;
#pragma unroll
        for (int i = 0; i < 4; ++i) { o0[i] = c0[i] * inv; o1[i] = c1[i] * inv; }
        *(f32x4*)(msg + (size_t)q * DIMN + d0)     = o0;   // msg aliases Qp (row q only)
        *(f32x4*)(msg + (size_t)q * DIMN + d0 + 4) = o1;
    }
}

// ---------------- final: x = query + msg@Wp^T + bp; LayerNorm ----------------
// Persistent grid: stage W into LDS ONCE per block, grid-stride over 64-row
// tiles (was: 1563 blocks x 64KB redundant staging).
__global__ __launch_bounds__(256, 2) void k_final(
        const float* __restrict__ msg, const __bf16* __restrict__ wh,
        const __bf16* __restrict__ wl, const float* __restrict__ bp,
        const float* __restrict__ query, const float* __restrict__ lng,
        const float* __restrict__ lnb, float* __restrict__ out, int M, int ntiles) {
    __shared__ __align__(16) __bf16 WH[128 * WPAD];
    __shared__ __align__(16) __bf16 WL[128 * WPAD];
    {
        const uint4* srcH = (const uint4*)wh;
        const uint4* srcL = (const uint4*)wl;
#pragma unroll
        for (int it = 0; it < 8; ++it) {
            int cid = threadIdx.x + it * 256;
            int n = cid >> 4, c16 = cid & 15;
            *(uint4*)((char*)WH + n * (WPAD * 2) + c16 * 16) = srcH[cid];
            *(uint4*)((char*)WL + n * (WPAD * 2) + c16 * 16) = srcL[cid];
        }
    }
    __syncthreads();

    int lane = threadIdx.x & 63;
    int wid  = threadIdx.x >> 6;
    int r = lane & 15, g = lane >> 4;

    for (int tile = blockIdx.x; tile < ntiles; tile += gridDim.x) {
        int rb = tile * 64 + wid * 16;

        int arow = rb + r; if (arow >= M) arow = M - 1;
        const float* xrow = msg + (size_t)arow * DIMN;
        bf16x8 Ah[4], Al[4];
#pragma unroll
        for (int ks = 0; ks < 4; ++ks) {
            const float* px = xrow + ks * 32 + g * 8;
            f32x4 v0 = *(const f32x4*)(px);
            f32x4 v1 = *(const f32x4*)(px + 4);
#pragma unroll
            for (int i = 0; i < 4; ++i) {
                __bf16 h0 = (__bf16)v0[i];
                __bf16 h1 = (__bf16)v1[i];
                Ah[ks][i]     = h0;
                Ah[ks][i + 4] = h1;
                Al[ks][i]     = (__bf16)(v0[i] - (float)h0);
                Al[ks][i + 4] = (__bf16)(v1[i] - (float)h1);
            }
        }
        float xv[8][4];
#pragma unroll
        for (int ct = 0; ct < 8; ++ct) {
            f32x4 acc = {0.f, 0.f, 0.f, 0.f};
            int n = ct * 16 + r;
#pragma unroll
            for (int ks = 0; ks < 4; ++ks) {
                bf16x8 Bh = *(const bf16x8*)(WH + n * WPAD + ks * 32 + g * 8);
                bf16x8 Bl = *(const bf16x8*)(WL + n * WPAD + ks * 32 + g * 8);
                acc = __builtin_amdgcn_mfma_f32_16x16x32_bf16(Ah[ks], Bh, acc, 0, 0, 0);
                acc = __builtin_amdgcn_mfma_f32_16x16x32_bf16(Ah[ks], Bl, acc, 0, 0, 0);
                acc = __builtin_amdgcn_mfma_f32_16x16x32_bf16(Al[ks], Bh, acc, 0, 0, 0);
            }
            float bn = bp[n];
#pragma unroll
            for (int i = 0; i < 4; ++i) {
                int row = rb + g * 4 + i;
                int rc = row < M ? row : M - 1;
                xv[ct][i] = acc[i] + bn + query[(size_t)rc * DIMN + n];
            }
        }
#pragma unroll
        for (int i = 0; i < 4; ++i) {
            float s = 0.f, ss = 0.f;
#pragma unroll
            for (int ct = 0; ct < 8; ++ct) { s += xv[ct][i]; ss += xv[ct][i] * xv[ct][i]; }
            s += __shfl_xor(s, 1, 64);  ss += __shfl_xor(ss, 1, 64);
            s += __shfl_xor(s, 2, 64);  ss += __shfl_xor(ss, 2, 64);
            s += __shfl_xor(s, 4, 64);  ss += __shfl_xor(ss, 4, 64);
            s += __shfl_xor(s, 8, 64);  ss += __shfl_xor(ss, 8, 64);
            float mean = s * (1.f / DIMN);
            float var  = ss * (1.f / DIMN) - mean * mean;
            float rstd = rsqrtf(var + LN_EPS);
            int row = rb + g * 4 + i;
#pragma unroll
            for (int ct = 0; ct < 8; ++ct) {
                int n = ct * 16 + r;
                if (row < M)
                    out[(size_t)row * DIMN + n] = (xv[ct][i] - mean) * rstd * lng[n] + lnb[n];
            }
        }
    }
}

extern "C" void kernel_launch(void* const* d_in, const int* in_sizes, int n_in,
                              void* d_out, int out_size, void* d_ws, size_t ws_size,
                              hipStream_t stream) {
    const float* query = (const float*)d_in[0];
    const float* keys  = (const float*)d_in[1];
    const float* values= (const float*)d_in[2];
    const int*   qidx  = (const int*)d_in[3];
    const int*   kidx  = (const int*)d_in[4];
    const float* Wq    = (const float*)d_in[5];
    const float* bq    = (const float*)d_in[6];
    const float* Wk    = (const float*)d_in[7];
    const float* bk    = (const float*)d_in[8];
    const float* Wv    = (const float*)d_in[9];
    const float* bv    = (const float*)d_in[10];
    const float* Wp    = (const float*)d_in[11];
    const float* bp    = (const float*)d_in[12];
    const float* a     = (const float*)d_in[13];
    const float* pw    = (const float*)d_in[14];
    const float* lng   = (const float*)d_in[15];
    const float* lnb   = (const float*)d_in[16];

    int NQ_ = in_sizes[0] / DIMN;
    int NK_ = in_sizes[1] / DIMN;
    int E_  = in_sizes[3];

    char* p = (char*)d_ws;
    __bf16* wsplit = (__bf16*)p;
    size_t off = (size_t)4 * 32768 * sizeof(__bf16);
    float*  Qp = (float*)(p + off);  off += (size_t)NQ_ * DIMN * 4;
    __bf16* KV = (__bf16*)(p + off); off += (size_t)NK_ * 256 * 2;
    int* counts = (int*)(p + off); off += (((size_t)NQ_ * 4) + 127) / 128 * 128;
    int* offs   = (int*)(p + off); off += (((size_t)NQ_ * 4) + 127) / 128 * 128;
    int* bsum   = (int*)(p + off); off += 1024 * 4;
    int* rank   = (int*)(p + off); off += (size_t)E_ * 4;
    int* skey   = (int*)(p + off); off += (size_t)E_ * 4;
    float* msg  = Qp;  // aliasing is safe: wave for query q reads only Qp row q

    hipMemsetAsync(counts, 0, (size_t)NQ_ * 4, stream);

    int ge = (E_ + 255) / 256;
    int gm = (NQ_ + 63) / 64;
    int nb = (NQ_ + 255) / 256;

    k_prep<<<256 + ge, 256, 0, stream>>>(Wq, Wk, Wv, Wp, wsplit, qidx, counts, rank, E_);

    int ntq = (NQ_ + 31) >> 5;
    int ntk = (NK_ + 31) >> 5;
    int total = ntq + 2 * ntk;
    int chunk = (total + 511) / 512;            // grid <= 512 blocks, 1 round
    int gproj = (total + chunk - 1) / chunk;
    if (gproj < nb) gproj = nb;                 // scan1 piggyback needs nb blocks
    k_proj3<<<gproj, 256, 0, stream>>>(query, keys, values, wsplit, bq, bk, bv,
                                       Qp, KV, NQ_, NK_, counts, offs, bsum, nb, chunk);

    k_scan2<<<1, 1024, 0, stream>>>(bsum, nb);

    k_scatter<<<ge, 256, 0, stream>>>(qidx, kidx, offs, bsum, rank, skey, E_);

    k_attn<<<(NQ_ + 3) / 4, 256, 0, stream>>>(Qp, KV, offs, bsum, skey, a, pw, msg, NQ_, E_);

    int gfin = gm < 512 ? gm : 512;
    k_final<<<gfin, 256, 0, stream>>>(msg, wsplit + 3 * 32768, wsplit + 3 * 32768 + 16384,
                                      bp, query, lng, lnb, (float*)d_out, NQ_, gm);
}

// Round 10
// 409.382 us; speedup vs baseline: 1.0070x; 1.0070x over previous
//
#include <hip/hip_runtime.h>
#include <hip/hip_bf16.h>

#define DIMN 128
#define LN_EPS 1e-5f
#define WPAD 136   // padded row length in bf16 (272 B = 17*16, keeps b128 aligned, ~2-way banks)
#define LOG2E 1.4426950408889634f

typedef __bf16 bf16x8 __attribute__((ext_vector_type(8)));
typedef float f32x4 __attribute__((ext_vector_type(4)));

__device__ __forceinline__ float bf_even(uint32_t u) {  // element at even dim (low 16 bits)
    union { uint32_t u; float f; } c; c.u = u << 16; return c.f;
}
// element at odd dim (high 16 bits) -- mask-free: low-16 garbage is <=2^-8
// relative noise (below the bf16 rounding already present), saves the AND.
__device__ __forceinline__ float bf_odd(uint32_t u) {
    union { uint32_t u; float f; } c; c.u = u; return c.f;
}

// ---------------- K1: W split (blocks 0..255) + hist/rank (rest) ----------------
__global__ __launch_bounds__(256) void k_prep(
        const float* __restrict__ Wq, const float* __restrict__ Wk,
        const float* __restrict__ Wv, const float* __restrict__ Wp,
        __bf16* __restrict__ wsplit, const int* __restrict__ qidx,
        int* __restrict__ counts, int* __restrict__ rank, int E) {
    int bi = blockIdx.x;
    if (bi < 256) {
        int w = bi >> 6;
        const float* W = (w == 0) ? Wq : (w == 1) ? Wk : (w == 2) ? Wv : Wp;
        __bf16* hi = wsplit + (size_t)w * 32768;
        __bf16* lo = hi + 16384;
        int i = (bi & 63) * 256 + threadIdx.x;
        float x = W[i];
        __bf16 h = (__bf16)x;
        hi[i] = h;
        lo[i] = (__bf16)(x - (float)h);
    } else {
        int i = (bi - 256) * 256 + threadIdx.x;
        if (i < E) rank[i] = atomicAdd(&counts[qidx[i]], 1);
    }
}

// ---------------- K2: LDS-W projections (+ scan1 in low blocks) ----------------
// chunk=5 (1875 blocks, ~3.7 scheduling rounds): fine-grained interleave of
// Q-mode (3-pass, ~2-3x cost) and K/V-mode (1-pass) blocks smooths the
// makespan. R9's chunk=19 single-round schedule regressed 50us: mode-pure
// Q-blocks became the critical path while K/V blocks idled.
__global__ __launch_bounds__(256, 2) void k_proj3(
        const float* __restrict__ query, const float* __restrict__ keys,
        const float* __restrict__ values, const __bf16* __restrict__ wsplit,
        const float* __restrict__ bq, const float* __restrict__ bk,
        const float* __restrict__ bv, float* __restrict__ Qp,
        __bf16* __restrict__ KV, int NQ_, int NK_,
        const int* __restrict__ counts, int* __restrict__ offs,
        int* __restrict__ bsum, int nb, int chunk) {
    __shared__ int s[256];
    __shared__ __align__(16) __bf16 WH[128 * WPAD];
    __shared__ __align__(16) __bf16 WL[128 * WPAD];

    // ---- scan1 piggyback (counts ready: k_prep ran before) ----
    if ((int)blockIdx.x < nb) {
        int t = threadIdx.x;
        int i = blockIdx.x * 256 + t;
        int v = (i < NQ_) ? counts[i] : 0;
        s[t] = v;
        __syncthreads();
        for (int o = 1; o < 256; o <<= 1) {
            int x = (t >= o) ? s[t - o] : 0;
            __syncthreads();
            s[t] += x;
            __syncthreads();
        }
        if (i < NQ_) offs[i] = s[t] - v;
        if (t == 255) bsum[blockIdx.x] = s[t];
    }

    int lane = threadIdx.x & 63;
    int wid  = threadIdx.x >> 6;
    int r = lane & 15, g = lane >> 4;
    int rowoff = (wid >> 1) * 16;   // 0 or 16 within the 32-row tile
    int chalf  = wid & 1;           // column half: cols [chalf*64, chalf*64+64)

    int ntq = (NQ_ + 31) >> 5;
    int ntk = (NK_ + 31) >> 5;
    int total = ntq + 2 * ntk;

    int t0 = blockIdx.x * chunk;
    int t1 = t0 + chunk; if (t1 > total) t1 = total;
    int staged = -1;
    float bias_n[4];

    for (int t = t0; t < t1; ++t) {
        int m, tt;
        if (t < ntq)            { m = 0; tt = t; }
        else if (t < ntq + ntk) { m = 1; tt = t - ntq; }
        else                    { m = 2; tt = t - ntq - ntk; }

        if (m != staged) {
            if (staged != -1) __syncthreads();   // drain readers of old W
            const uint4* srcH = (const uint4*)(wsplit + (size_t)m * 32768);
#pragma unroll
            for (int it = 0; it < 8; ++it) {
                int cid = threadIdx.x + it * 256;     // 2048 16B-chunks per plane
                int n = cid >> 4, c16 = cid & 15;
                *(uint4*)((char*)WH + n * (WPAD * 2) + c16 * 16) = srcH[cid];
            }
            if (m == 0) {                             // WL only needed for 3-pass Q
                const uint4* srcL = (const uint4*)(wsplit + (size_t)m * 32768 + 16384);
#pragma unroll
                for (int it = 0; it < 8; ++it) {
                    int cid = threadIdx.x + it * 256;
                    int n = cid >> 4, c16 = cid & 15;
                    *(uint4*)((char*)WL + n * (WPAD * 2) + c16 * 16) = srcL[cid];
                }
            }
            __syncthreads();
            staged = m;
            const float* bias = (m == 0) ? bq : (m == 1) ? bk : bv;
#pragma unroll
            for (int c = 0; c < 4; ++c) bias_n[c] = bias[(chalf * 4 + c) * 16 + r];
        }

        const float* X = (m == 0) ? query : (m == 1) ? keys : values;
        int M = (m == 0) ? NQ_ : NK_;
        int rb = tt * 32 + rowoff;
        int arow = rb + r; if (arow >= M) arow = M - 1;
        const float* xrow = X + (size_t)arow * DIMN;

        bf16x8 Ah[4], Al[4];
#pragma unroll
        for (int ks = 0; ks < 4; ++ks) {
            const float* px = xrow + ks * 32 + g * 8;
            f32x4 v0 = *(const f32x4*)(px);
            f32x4 v1 = *(const f32x4*)(px + 4);
#pragma unroll
            for (int i = 0; i < 4; ++i) {
                __bf16 h0 = (__bf16)v0[i];
                __bf16 h1 = (__bf16)v1[i];
                Ah[ks][i]     = h0;
                Ah[ks][i + 4] = h1;
                if (m == 0) {
                    Al[ks][i]     = (__bf16)(v0[i] - (float)h0);
                    Al[ks][i + 4] = (__bf16)(v1[i] - (float)h1);
                }
            }
        }

        f32x4 acc[4];
#pragma unroll
        for (int c = 0; c < 4; ++c) {
            acc[c] = (f32x4){0.f, 0.f, 0.f, 0.f};
            int n = (chalf * 4 + c) * 16 + r;
#pragma unroll
            for (int ks = 0; ks < 4; ++ks) {
                bf16x8 Bh = *(const bf16x8*)(WH + n * WPAD + ks * 32 + g * 8);
                acc[c] = __builtin_amdgcn_mfma_f32_16x16x32_bf16(Ah[ks], Bh, acc[c], 0, 0, 0);
                if (m == 0) {
                    bf16x8 Bl = *(const bf16x8*)(WL + n * WPAD + ks * 32 + g * 8);
                    acc[c] = __builtin_amdgcn_mfma_f32_16x16x32_bf16(Ah[ks], Bl, acc[c], 0, 0, 0);
                    acc[c] = __builtin_amdgcn_mfma_f32_16x16x32_bf16(Al[ks], Bh, acc[c], 0, 0, 0);
                }
            }
        }

        if (m == 0) {
#pragma unroll
            for (int c = 0; c < 4; ++c) {
                int n = (chalf * 4 + c) * 16 + r;
#pragma unroll
                for (int i = 0; i < 4; ++i) {
                    int row = rb + g * 4 + i;
                    if (row < M) Qp[(size_t)row * DIMN + n] = acc[c][i] + bias_n[c];
                }
            }
        } else {
            int vofs = (m == 2) ? 128 : 0;
#pragma unroll
            for (int c = 0; c < 4; ++c) {
                int n = (chalf * 4 + c) * 16 + r;
#pragma unroll
                for (int i = 0; i < 4; ++i) {
                    int row = rb + g * 4 + i;
                    if (row < M) KV[(size_t)row * 256 + vofs + n] = (__bf16)(acc[c][i] + bias_n[c]);
                }
            }
        }
    }
}

__global__ __launch_bounds__(1024) void k_scan2(int* __restrict__ bsum, int nb) {
    __shared__ int s[1024];
    int t = threadIdx.x;
    int v = (t < nb) ? bsum[t] : 0;
    s[t] = v;
    __syncthreads();
    for (int o = 1; o < 1024; o <<= 1) {
        int x = (t >= o) ? s[t - o] : 0;
        __syncthreads();
        s[t] += x;
        __syncthreads();
    }
    if (t < nb) bsum[t] = s[t];  // inclusive block-sum scan
}

// final offset of query i = offs[i] + (i>=256 ? bsum[i/256-1] : 0)
__global__ void k_scatter(const int* __restrict__ qidx, const int* __restrict__ kidx,
                          const int* __restrict__ offs, const int* __restrict__ bsum,
                          const int* __restrict__ rank, int* __restrict__ skey, int E) {
    int i = blockIdx.x * 256 + threadIdx.x;
    if (i < E) {
        int q = qidx[i];
        int base = offs[q] + ((q >= 256) ? bsum[(q >> 8) - 1] : 0);
        skey[base + rank[i]] = kidx[i];
    }
}

// ---------------- per-query softmax aggregation ----------------
// 4 edges per wave (16 lanes / edge, 8 dims / lane), x3 batched: 12 edges and
// 6 independent dwordx4 KV gathers in flight per wave iteration.
__device__ __forceinline__ float score8(uint4 ku, const f32x4& qa, const f32x4& qb,
                                        const f32x4& aa, const f32x4& ab, float pw) {
    float e, x;
    x = qa[0] + bf_even(ku.x); x = x >= 0.f ? x : pw * x; e  = aa[0] * x;
    x = qa[1] + bf_odd (ku.x); x = x >= 0.f ? x : pw * x; e += aa[1] * x;
    x = qa[2] + bf_even(ku.y); x = x >= 0.f ? x : pw * x; e += aa[2] * x;
    x = qa[3] + bf_odd (ku.y); x = x >= 0.f ? x : pw * x; e += aa[3] * x;
    x = qb[0] + bf_even(ku.z); x = x >= 0.f ? x : pw * x; e += ab[0] * x;
    x = qb[1] + bf_odd (ku.z); x = x >= 0.f ? x : pw * x; e += ab[1] * x;
    x = qb[2] + bf_even(ku.w); x = x >= 0.f ? x : pw * x; e += ab[2] * x;
    x = qb[3] + bf_odd (ku.w); x = x >= 0.f ? x : pw * x; e += ab[3] * x;
    return e;
}

__device__ __forceinline__ void acc8(uint4 vu, float w, f32x4& c0, f32x4& c1) {
    c0[0] += w * bf_even(vu.x); c0[1] += w * bf_odd(vu.x);
    c0[2] += w * bf_even(vu.y); c0[3] += w * bf_odd(vu.y);
    c1[0] += w * bf_even(vu.z); c1[1] += w * bf_odd(vu.z);
    c1[2] += w * bf_even(vu.w); c1[3] += w * bf_odd(vu.w);
}

__device__ __forceinline__ float red1(float v) {   // += partner lane (xor 1)
    return v + __int_as_float(__builtin_amdgcn_ds_swizzle(__float_as_int(v), 0x041F));
}
__device__ __forceinline__ float redg(float v) {   // += across the 4 edge groups
    v += __int_as_float(__builtin_amdgcn_ds_swizzle(__float_as_int(v), 0x401F)); // xor16
    v += __shfl_xor(v, 32, 64);                                                  // xor32
    return v;
}

__global__ __launch_bounds__(256) void k_attn(
        const float* __restrict__ Qp, const __bf16* __restrict__ KV,
        const int* __restrict__ offs, const int* __restrict__ bsum,
        const int* __restrict__ skey, const float* __restrict__ a,
        const float* __restrict__ prelu_w, float* __restrict__ msg,
        int NQ_, int E_) {
    int lane = threadIdx.x & 63;
    int q = blockIdx.x * 4 + (threadIdx.x >> 6);
    if (q >= NQ_) return;
    int l16 = lane & 15;
    int grp = lane >> 4;
    int d0 = l16 * 8;

    f32x4 aa = *(const f32x4*)(a + d0);
    f32x4 ab = *(const f32x4*)(a + d0 + 4);
#pragma unroll
    for (int i = 0; i < 4; ++i) { aa[i] *= LOG2E; ab[i] *= LOG2E; }  // exp -> exp2
    f32x4 qa = *(const f32x4*)(Qp + (size_t)q * DIMN + d0);
    f32x4 qb = *(const f32x4*)(Qp + (size_t)q * DIMN + d0 + 4);
    float pw = prelu_w[0];

    int beg = offs[q] + ((q >= 256) ? bsum[(q >> 8) - 1] : 0);
    int qn = q + 1;
    int end = (qn == NQ_) ? E_ : offs[qn] + ((qn >= 256) ? bsum[(qn >> 8) - 1] : 0);

    float den = 0.f;
    f32x4 c0 = {0.f, 0.f, 0.f, 0.f}, c1 = {0.f, 0.f, 0.f, 0.f};
    int j = beg;
    for (; j + 12 <= end; j += 12) {        // 12 edges, 6 KV gathers in flight
        int k0 = skey[j + grp];
        int k1 = skey[j + 4 + grp];
        int k2 = skey[j + 8 + grp];
        const uint4* r0 = (const uint4*)(KV + ((size_t)k0 << 8));
        const uint4* r1 = (const uint4*)(KV + ((size_t)k1 << 8));
        const uint4* r2 = (const uint4*)(KV + ((size_t)k2 << 8));
        uint4 ku0 = r0[l16], vu0 = r0[16 + l16];
        uint4 ku1 = r1[l16], vu1 = r1[16 + l16];
        uint4 ku2 = r2[l16], vu2 = r2[16 + l16];
        float e0 = red1(score8(ku0, qa, qb, aa, ab, pw));
        float e1 = red1(score8(ku1, qa, qb, aa, ab, pw));
        float e2 = red1(score8(ku2, qa, qb, aa, ab, pw));
        float w0 = exp2f(e0), w1 = exp2f(e1), w2 = exp2f(e2);
        den += w0 + w1 + w2;
        acc8(vu0, w0, c0, c1);
        acc8(vu1, w1, c0, c1);
        acc8(vu2, w2, c0, c1);
    }
    for (; j < end; j += 4) {               // masked remainder (<=11 edges)
        int jj = j + grp;
        int k = skey[jj < end ? jj : end - 1];
        const uint4* r_ = (const uint4*)(KV + ((size_t)k << 8));
        uint4 ku = r_[l16], vu = r_[16 + l16];
        float e = red1(score8(ku, qa, qb, aa, ab, pw));
        float w = (jj < end) ? exp2f(e) : 0.f;
        den += w;
        acc8(vu, w, c0, c1);
    }

#pragma unroll
    for (int i = 0; i < 4; ++i) { c0[i] = redg(c0[i]); c1[i] = redg(c1[i]); }
    den = redg(den);
    float inv = den > 0.f ? 1.f / den : 0.f;
    if (grp == 0) {
        f32x4 o0, o1;
#pragma unroll
        for (int i = 0; i < 4; ++i) { o0[i] = c0[i] * inv; o1[i] = c1[i] * inv; }
        *(f32x4*)(msg + (size_t)q * DIMN + d0)     = o0;   // msg aliases Qp (row q only)
        *(f32x4*)(msg + (size_t)q * DIMN + d0 + 4) = o1;
    }
}

// ---------------- final: x = query + msg@Wp^T + bp; LayerNorm ----------------
// Persistent grid: stage W into LDS ONCE per block, grid-stride over 64-row
// tiles (uniform tile cost -> no makespan risk, unlike proj3's mode mix).
__global__ __launch_bounds__(256, 2) void k_final(
        const float* __restrict__ msg, const __bf16* __restrict__ wh,
        const __bf16* __restrict__ wl, const float* __restrict__ bp,
        const float* __restrict__ query, const float* __restrict__ lng,
        const float* __restrict__ lnb, float* __restrict__ out, int M, int ntiles) {
    __shared__ __align__(16) __bf16 WH[128 * WPAD];
    __shared__ __align__(16) __bf16 WL[128 * WPAD];
    {
        const uint4* srcH = (const uint4*)wh;
        const uint4* srcL = (const uint4*)wl;
#pragma unroll
        for (int it = 0; it < 8; ++it) {
            int cid = threadIdx.x + it * 256;
            int n = cid >> 4, c16 = cid & 15;
            *(uint4*)((char*)WH + n * (WPAD * 2) + c16 * 16) = srcH[cid];
            *(uint4*)((char*)WL + n * (WPAD * 2) + c16 * 16) = srcL[cid];
        }
    }
    __syncthreads();

    int lane = threadIdx.x & 63;
    int wid  = threadIdx.x >> 6;
    int r = lane & 15, g = lane >> 4;

    for (int tile = blockIdx.x; tile < ntiles; tile += gridDim.x) {
        int rb = tile * 64 + wid * 16;

        int arow = rb + r; if (arow >= M) arow = M - 1;
        const float* xrow = msg + (size_t)arow * DIMN;
        bf16x8 Ah[4], Al[4];
#pragma unroll
        for (int ks = 0; ks < 4; ++ks) {
            const float* px = xrow + ks * 32 + g * 8;
            f32x4 v0 = *(const f32x4*)(px);
            f32x4 v1 = *(const f32x4*)(px + 4);
#pragma unroll
            for (int i = 0; i < 4; ++i) {
                __bf16 h0 = (__bf16)v0[i];
                __bf16 h1 = (__bf16)v1[i];
                Ah[ks][i]     = h0;
                Ah[ks][i + 4] = h1;
                Al[ks][i]     = (__bf16)(v0[i] - (float)h0);
                Al[ks][i + 4] = (__bf16)(v1[i] - (float)h1);
            }
        }
        float xv[8][4];
#pragma unroll
        for (int ct = 0; ct < 8; ++ct) {
            f32x4 acc = {0.f, 0.f, 0.f, 0.f};
            int n = ct * 16 + r;
#pragma unroll
            for (int ks = 0; ks < 4; ++ks) {
                bf16x8 Bh = *(const bf16x8*)(WH + n * WPAD + ks * 32 + g * 8);
                bf16x8 Bl = *(const bf16x8*)(WL + n * WPAD + ks * 32 + g * 8);
                acc = __builtin_amdgcn_mfma_f32_16x16x32_bf16(Ah[ks], Bh, acc, 0, 0, 0);
                acc = __builtin_amdgcn_mfma_f32_16x16x32_bf16(Ah[ks], Bl, acc, 0, 0, 0);
                acc = __builtin_amdgcn_mfma_f32_16x16x32_bf16(Al[ks], Bh, acc, 0, 0, 0);
            }
            float bn = bp[n];
#pragma unroll
            for (int i = 0; i < 4; ++i) {
                int row = rb + g * 4 + i;
                int rc = row < M ? row : M - 1;
                xv[ct][i] = acc[i] + bn + query[(size_t)rc * DIMN + n];
            }
        }
#pragma unroll
        for (int i = 0; i < 4; ++i) {
            float s = 0.f, ss = 0.f;
#pragma unroll
            for (int ct = 0; ct < 8; ++ct) { s += xv[ct][i]; ss += xv[ct][i] * xv[ct][i]; }
            s += __shfl_xor(s, 1, 64);  ss += __shfl_xor(ss, 1, 64);
            s += __shfl_xor(s, 2, 64);  ss += __shfl_xor(ss, 2, 64);
            s += __shfl_xor(s, 4, 64);  ss += __shfl_xor(ss, 4, 64);
            s += __shfl_xor(s, 8, 64);  ss += __shfl_xor(ss, 8, 64);
            float mean = s * (1.f / DIMN);
            float var  = ss * (1.f / DIMN) - mean * mean;
            float rstd = rsqrtf(var + LN_EPS);
            int row = rb + g * 4 + i;
#pragma unroll
            for (int ct = 0; ct < 8; ++ct) {
                int n = ct * 16 + r;
                if (row < M)
                    out[(size_t)row * DIMN + n] = (xv[ct][i] - mean) * rstd * lng[n] + lnb[n];
            }
        }
    }
}

extern "C" void kernel_launch(void* const* d_in, const int* in_sizes, int n_in,
                              void* d_out, int out_size, void* d_ws, size_t ws_size,
                              hipStream_t stream) {
    const float* query = (const float*)d_in[0];
    const float* keys  = (const float*)d_in[1];
    const float* values= (const float*)d_in[2];
    const int*   qidx  = (const int*)d_in[3];
    const int*   kidx  = (const int*)d_in[4];
    const float* Wq    = (const float*)d_in[5];
    const float* bq    = (const float*)d_in[6];
    const float* Wk    = (const float*)d_in[7];
    const float* bk    = (const float*)d_in[8];
    const float* Wv    = (const float*)d_in[9];
    const float* bv    = (const float*)d_in[10];
    const float* Wp    = (const float*)d_in[11];
    const float* bp    = (const float*)d_in[12];
    const float* a     = (const float*)d_in[13];
    const float* pw    = (const float*)d_in[14];
    const float* lng   = (const float*)d_in[15];
    const float* lnb   = (const float*)d_in[16];

    int NQ_ = in_sizes[0] / DIMN;
    int NK_ = in_sizes[1] / DIMN;
    int E_  = in_sizes[3];

    char* p = (char*)d_ws;
    __bf16* wsplit = (__bf16*)p;
    size_t off = (size_t)4 * 32768 * sizeof(__bf16);
    float*  Qp = (float*)(p + off);  off += (size_t)NQ_ * DIMN * 4;
    __bf16* KV = (__bf16*)(p + off); off += (size_t)NK_ * 256 * 2;
    int* counts = (int*)(p + off); off += (((size_t)NQ_ * 4) + 127) / 128 * 128;
    int* offs   = (int*)(p + off); off += (((size_t)NQ_ * 4) + 127) / 128 * 128;
    int* bsum   = (int*)(p + off); off += 1024 * 4;
    int* rank   = (int*)(p + off); off += (size_t)E_ * 4;
    int* skey   = (int*)(p + off); off += (size_t)E_ * 4;
    float* msg  = Qp;  // aliasing is safe: wave for query q reads only Qp row q

    hipMemsetAsync(counts, 0, (size_t)NQ_ * 4, stream);

    int ge = (E_ + 255) / 256;
    int gm = (NQ_ + 63) / 64;
    int nb = (NQ_ + 255) / 256;

    k_prep<<<256 + ge, 256, 0, stream>>>(Wq, Wk, Wv, Wp, wsplit, qidx, counts, rank, E_);

    int ntq = (NQ_ + 31) >> 5;
    int ntk = (NK_ + 31) >> 5;
    int total = ntq + 2 * ntk;
    int chunk = 5;                              // fine-grained: ~3.7 rounds, balanced
    int gproj = (total + chunk - 1) / chunk;
    if (gproj < nb) gproj = nb;                 // scan1 piggyback needs nb blocks
    k_proj3<<<gproj, 256, 0, stream>>>(query, keys, values, wsplit, bq, bk, bv,
                                       Qp, KV, NQ_, NK_, counts, offs, bsum, nb, chunk);

    k_scan2<<<1, 1024, 0, stream>>>(bsum, nb);

    k_scatter<<<ge, 256, 0, stream>>>(qidx, kidx, offs, bsum, rank, skey, E_);

    k_attn<<<(NQ_ + 3) / 4, 256, 0, stream>>>(Qp, KV, offs, bsum, skey, a, pw, msg, NQ_, E_);

    int gfin = gm < 512 ? gm : 512;
    k_final<<<gfin, 256, 0, stream>>>(msg, wsplit + 3 * 32768, wsplit + 3 * 32768 + 16384,
                                      bp, query, lng, lnb, (float*)d_out, NQ_, gm);
}

// Round 11
// 361.776 us; speedup vs baseline: 1.1395x; 1.1316x over previous
//
#include <hip/hip_runtime.h>
#include <hip/hip_bf16.h>

#define DIMN 128
#define LN_EPS 1e-5f
#define WPAD 136   // padded row length in bf16 (272 B = 17*16, keeps b128 aligned, ~2-way banks)
#define LOG2E 1.4426950408889634f

typedef __bf16 bf16x8 __attribute__((ext_vector_type(8)));
typedef float f32x4 __attribute__((ext_vector_type(4)));

__device__ __forceinline__ float bf_even(uint32_t u) {  // element at even dim (low 16 bits)
    union { uint32_t u; float f; } c; c.u = u << 16; return c.f;
}
// element at odd dim (high 16 bits) -- mask-free: low-16 garbage is <=2^-8
// relative noise (below the bf16 rounding already present), saves the AND.
__device__ __forceinline__ float bf_odd(uint32_t u) {
    union { uint32_t u; float f; } c; c.u = u; return c.f;
}

// ---------------- K1: W split (blocks 0..255) + hist/rank (rest) ----------------
__global__ __launch_bounds__(256) void k_prep(
        const float* __restrict__ Wq, const float* __restrict__ Wk,
        const float* __restrict__ Wv, const float* __restrict__ Wp,
        __bf16* __restrict__ wsplit, const int* __restrict__ qidx,
        int* __restrict__ counts, int* __restrict__ rank, int E) {
    int bi = blockIdx.x;
    if (bi < 256) {
        int w = bi >> 6;
        const float* W = (w == 0) ? Wq : (w == 1) ? Wk : (w == 2) ? Wv : Wp;
        __bf16* hi = wsplit + (size_t)w * 32768;
        __bf16* lo = hi + 16384;
        int i = (bi & 63) * 256 + threadIdx.x;
        float x = W[i];
        __bf16 h = (__bf16)x;
        hi[i] = h;
        lo[i] = (__bf16)(x - (float)h);
    } else {
        int i = (bi - 256) * 256 + threadIdx.x;
        if (i < E) rank[i] = atomicAdd(&counts[qidx[i]], 1);
    }
}

// ---------------- K2: LDS-W projections (+ scan1 in low blocks) ----------------
// chunk=5 (1875 blocks, ~3.7 scheduling rounds): fine-grained interleave of
// Q-mode (3-pass, ~2-3x cost) and K/V-mode (1-pass) blocks smooths the
// makespan. chunk=19 single-round (R9) regressed 50us: mode-pure Q-blocks
// became the critical path while K/V blocks idled.
__global__ __launch_bounds__(256, 2) void k_proj3(
        const float* __restrict__ query, const float* __restrict__ keys,
        const float* __restrict__ values, const __bf16* __restrict__ wsplit,
        const float* __restrict__ bq, const float* __restrict__ bk,
        const float* __restrict__ bv, float* __restrict__ Qp,
        __bf16* __restrict__ KV, int NQ_, int NK_,
        const int* __restrict__ counts, int* __restrict__ offs,
        int* __restrict__ bsum, int nb, int chunk) {
    __shared__ int s[256];
    __shared__ __align__(16) __bf16 WH[128 * WPAD];
    __shared__ __align__(16) __bf16 WL[128 * WPAD];

    // ---- scan1 piggyback (counts ready: k_prep ran before) ----
    if ((int)blockIdx.x < nb) {
        int t = threadIdx.x;
        int i = blockIdx.x * 256 + t;
        int v = (i < NQ_) ? counts[i] : 0;
        s[t] = v;
        __syncthreads();
        for (int o = 1; o < 256; o <<= 1) {
            int x = (t >= o) ? s[t - o] : 0;
            __syncthreads();
            s[t] += x;
            __syncthreads();
        }
        if (i < NQ_) offs[i] = s[t] - v;
        if (t == 255) bsum[blockIdx.x] = s[t];
    }

    int lane = threadIdx.x & 63;
    int wid  = threadIdx.x >> 6;
    int r = lane & 15, g = lane >> 4;
    int rowoff = (wid >> 1) * 16;   // 0 or 16 within the 32-row tile
    int chalf  = wid & 1;           // column half: cols [chalf*64, chalf*64+64)

    int ntq = (NQ_ + 31) >> 5;
    int ntk = (NK_ + 31) >> 5;
    int total = ntq + 2 * ntk;

    int t0 = blockIdx.x * chunk;
    int t1 = t0 + chunk; if (t1 > total) t1 = total;
    int staged = -1;
    float bias_n[4];

    for (int t = t0; t < t1; ++t) {
        int m, tt;
        if (t < ntq)            { m = 0; tt = t; }
        else if (t < ntq + ntk) { m = 1; tt = t - ntq; }
        else                    { m = 2; tt = t - ntq - ntk; }

        if (m != staged) {
            if (staged != -1) __syncthreads();   // drain readers of old W
            const uint4* srcH = (const uint4*)(wsplit + (size_t)m * 32768);
#pragma unroll
            for (int it = 0; it < 8; ++it) {
                int cid = threadIdx.x + it * 256;     // 2048 16B-chunks per plane
                int n = cid >> 4, c16 = cid & 15;
                *(uint4*)((char*)WH + n * (WPAD * 2) + c16 * 16) = srcH[cid];
            }
            if (m == 0) {                             // WL only needed for 3-pass Q
                const uint4* srcL = (const uint4*)(wsplit + (size_t)m * 32768 + 16384);
#pragma unroll
                for (int it = 0; it < 8; ++it) {
                    int cid = threadIdx.x + it * 256;
                    int n = cid >> 4, c16 = cid & 15;
                    *(uint4*)((char*)WL + n * (WPAD * 2) + c16 * 16) = srcL[cid];
                }
            }
            __syncthreads();
            staged = m;
            const float* bias = (m == 0) ? bq : (m == 1) ? bk : bv;
#pragma unroll
            for (int c = 0; c < 4; ++c) bias_n[c] = bias[(chalf * 4 + c) * 16 + r];
        }

        const float* X = (m == 0) ? query : (m == 1) ? keys : values;
        int M = (m == 0) ? NQ_ : NK_;
        int rb = tt * 32 + rowoff;
        int arow = rb + r; if (arow >= M) arow = M - 1;
        const float* xrow = X + (size_t)arow * DIMN;

        bf16x8 Ah[4], Al[4];
#pragma unroll
        for (int ks = 0; ks < 4; ++ks) {
            const float* px = xrow + ks * 32 + g * 8;
            f32x4 v0 = *(const f32x4*)(px);
            f32x4 v1 = *(const f32x4*)(px + 4);
#pragma unroll
            for (int i = 0; i < 4; ++i) {
                __bf16 h0 = (__bf16)v0[i];
                __bf16 h1 = (__bf16)v1[i];
                Ah[ks][i]     = h0;
                Ah[ks][i + 4] = h1;
                if (m == 0) {
                    Al[ks][i]     = (__bf16)(v0[i] - (float)h0);
                    Al[ks][i + 4] = (__bf16)(v1[i] - (float)h1);
                }
            }
        }

        f32x4 acc[4];
#pragma unroll
        for (int c = 0; c < 4; ++c) {
            acc[c] = (f32x4){0.f, 0.f, 0.f, 0.f};
            int n = (chalf * 4 + c) * 16 + r;
#pragma unroll
            for (int ks = 0; ks < 4; ++ks) {
                bf16x8 Bh = *(const bf16x8*)(WH + n * WPAD + ks * 32 + g * 8);
                acc[c] = __builtin_amdgcn_mfma_f32_16x16x32_bf16(Ah[ks], Bh, acc[c], 0, 0, 0);
                if (m == 0) {
                    bf16x8 Bl = *(const bf16x8*)(WL + n * WPAD + ks * 32 + g * 8);
                    acc[c] = __builtin_amdgcn_mfma_f32_16x16x32_bf16(Ah[ks], Bl, acc[c], 0, 0, 0);
                    acc[c] = __builtin_amdgcn_mfma_f32_16x16x32_bf16(Al[ks], Bh, acc[c], 0, 0, 0);
                }
            }
        }

        if (m == 0) {
#pragma unroll
            for (int c = 0; c < 4; ++c) {
                int n = (chalf * 4 + c) * 16 + r;
#pragma unroll
                for (int i = 0; i < 4; ++i) {
                    int row = rb + g * 4 + i;
                    if (row < M) Qp[(size_t)row * DIMN + n] = acc[c][i] + bias_n[c];
                }
            }
        } else {
            int vofs = (m == 2) ? 128 : 0;
#pragma unroll
            for (int c = 0; c < 4; ++c) {
                int n = (chalf * 4 + c) * 16 + r;
#pragma unroll
                for (int i = 0; i < 4; ++i) {
                    int row = rb + g * 4 + i;
                    if (row < M) KV[(size_t)row * 256 + vofs + n] = (__bf16)(acc[c][i] + bias_n[c]);
                }
            }
        }
    }
}

__global__ __launch_bounds__(1024) void k_scan2(int* __restrict__ bsum, int nb) {
    __shared__ int s[1024];
    int t = threadIdx.x;
    int v = (t < nb) ? bsum[t] : 0;
    s[t] = v;
    __syncthreads();
    for (int o = 1; o < 1024; o <<= 1) {
        int x = (t >= o) ? s[t - o] : 0;
        __syncthreads();
        s[t] += x;
        __syncthreads();
    }
    if (t < nb) bsum[t] = s[t];  // inclusive block-sum scan
}

// final offset of query i = offs[i] + (i>=256 ? bsum[i/256-1] : 0)
__global__ void k_scatter(const int* __restrict__ qidx, const int* __restrict__ kidx,
                          const int* __restrict__ offs, const int* __restrict__ bsum,
                          const int* __restrict__ rank, int* __restrict__ skey, int E) {
    int i = blockIdx.x * 256 + threadIdx.x;
    if (i < E) {
        int q = qidx[i];
        int base = offs[q] + ((q >= 256) ? bsum[(q >> 8) - 1] : 0);
        skey[base + rank[i]] = kidx[i];
    }
}

// ---------------- per-query softmax aggregation ----------------
// 4 edges per wave (16 lanes / edge, 8 dims / lane), x3 batched: 12 edges and
// 6 independent dwordx4 KV gathers in flight per wave iteration.
__device__ __forceinline__ float score8(uint4 ku, const f32x4& qa, const f32x4& qb,
                                        const f32x4& aa, const f32x4& ab, float pw) {
    float e, x;
    x = qa[0] + bf_even(ku.x); x = x >= 0.f ? x : pw * x; e  = aa[0] * x;
    x = qa[1] + bf_odd (ku.x); x = x >= 0.f ? x : pw * x; e += aa[1] * x;
    x = qa[2] + bf_even(ku.y); x = x >= 0.f ? x : pw * x; e += aa[2] * x;
    x = qa[3] + bf_odd (ku.y); x = x >= 0.f ? x : pw * x; e += aa[3] * x;
    x = qb[0] + bf_even(ku.z); x = x >= 0.f ? x : pw * x; e += ab[0] * x;
    x = qb[1] + bf_odd (ku.z); x = x >= 0.f ? x : pw * x; e += ab[1] * x;
    x = qb[2] + bf_even(ku.w); x = x >= 0.f ? x : pw * x; e += ab[2] * x;
    x = qb[3] + bf_odd (ku.w); x = x >= 0.f ? x : pw * x; e += ab[3] * x;
    return e;
}

__device__ __forceinline__ void acc8(uint4 vu, float w, f32x4& c0, f32x4& c1) {
    c0[0] += w * bf_even(vu.x); c0[1] += w * bf_odd(vu.x);
    c0[2] += w * bf_even(vu.y); c0[3] += w * bf_odd(vu.y);
    c1[0] += w * bf_even(vu.z); c1[1] += w * bf_odd(vu.z);
    c1[2] += w * bf_even(vu.w); c1[3] += w * bf_odd(vu.w);
}

__device__ __forceinline__ float red1(float v) {   // += partner lane (xor 1)
    return v + __int_as_float(__builtin_amdgcn_ds_swizzle(__float_as_int(v), 0x041F));
}
__device__ __forceinline__ float redg(float v) {   // += across the 4 edge groups
    v += __int_as_float(__builtin_amdgcn_ds_swizzle(__float_as_int(v), 0x401F)); // xor16
    v += __shfl_xor(v, 32, 64);                                                  // xor32
    return v;
}

__global__ __launch_bounds__(256) void k_attn(
        const float* __restrict__ Qp, const __bf16* __restrict__ KV,
        const int* __restrict__ offs, const int* __restrict__ bsum,
        const int* __restrict__ skey, const float* __restrict__ a,
        const float* __restrict__ prelu_w, float* __restrict__ msg,
        int NQ_, int E_) {
    int lane = threadIdx.x & 63;
    int q = blockIdx.x * 4 + (threadIdx.x >> 6);
    if (q >= NQ_) return;
    int l16 = lane & 15;
    int grp = lane >> 4;
    int d0 = l16 * 8;

    f32x4 aa = *(const f32x4*)(a + d0);
    f32x4 ab = *(const f32x4*)(a + d0 + 4);
#pragma unroll
    for (int i = 0; i < 4; ++i) { aa[i] *= LOG2E; ab[i] *= LOG2E; }  // exp -> exp2
    f32x4 qa = *(const f32x4*)(Qp + (size_t)q * DIMN + d0);
    f32x4 qb = *(const f32x4*)(Qp + (size_t)q * DIMN + d0 + 4);
    float pw = prelu_w[0];

    int beg = offs[q] + ((q >= 256) ? bsum[(q >> 8) - 1] : 0);
    int qn = q + 1;
    int end = (qn == NQ_) ? E_ : offs[qn] + ((qn >= 256) ? bsum[(qn >> 8) - 1] : 0);

    float den = 0.f;
    f32x4 c0 = {0.f, 0.f, 0.f, 0.f}, c1 = {0.f, 0.f, 0.f, 0.f};
    int j = beg;
    for (; j + 12 <= end; j += 12) {        // 12 edges, 6 KV gathers in flight
        int k0 = skey[j + grp];
        int k1 = skey[j + 4 + grp];
        int k2 = skey[j + 8 + grp];
        const uint4* r0 = (const uint4*)(KV + ((size_t)k0 << 8));
        const uint4* r1 = (const uint4*)(KV + ((size_t)k1 << 8));
        const uint4* r2 = (const uint4*)(KV + ((size_t)k2 << 8));
        uint4 ku0 = r0[l16], vu0 = r0[16 + l16];
        uint4 ku1 = r1[l16], vu1 = r1[16 + l16];
        uint4 ku2 = r2[l16], vu2 = r2[16 + l16];
        float e0 = red1(score8(ku0, qa, qb, aa, ab, pw));
        float e1 = red1(score8(ku1, qa, qb, aa, ab, pw));
        float e2 = red1(score8(ku2, qa, qb, aa, ab, pw));
        float w0 = exp2f(e0), w1 = exp2f(e1), w2 = exp2f(e2);
        den += w0 + w1 + w2;
        acc8(vu0, w0, c0, c1);
        acc8(vu1, w1, c0, c1);
        acc8(vu2, w2, c0, c1);
    }
    for (; j < end; j += 4) {               // masked remainder (<=11 edges)
        int jj = j + grp;
        int k = skey[jj < end ? jj : end - 1];
        const uint4* r_ = (const uint4*)(KV + ((size_t)k << 8));
        uint4 ku = r_[l16], vu = r_[16 + l16];
        float e = red1(score8(ku, qa, qb, aa, ab, pw));
        float w = (jj < end) ? exp2f(e) : 0.f;
        den += w;
        acc8(vu, w, c0, c1);
    }

#pragma unroll
    for (int i = 0; i < 4; ++i) { c0[i] = redg(c0[i]); c1[i] = redg(c1[i]); }
    den = redg(den);
    float inv = den > 0.f ? 1.f / den : 0.f;
    if (grp == 0) {
        f32x4 o0, o1;
#pragma unroll
        for (int i = 0; i < 4; ++i) { o0[i] = c0[i] * inv; o1[i] = c1[i] * inv; }
        *(f32x4*)(msg + (size_t)q * DIMN + d0)     = o0;   // msg aliases Qp (row q only)
        *(f32x4*)(msg + (size_t)q * DIMN + d0 + 4) = o1;
    }
}

// ---------------- final: x = query + msg@Wp^T + bp; LayerNorm ----------------
// Per-block W staging + one 64-row tile per block (R8 form). The persistent
// 512-block variant regressed ~47us: both LDS-resident blocks per CU lock
// into the same phase; short blocks get arrival pipelining instead.
__global__ __launch_bounds__(256, 2) void k_final(
        const float* __restrict__ msg, const __bf16* __restrict__ wh,
        const __bf16* __restrict__ wl, const float* __restrict__ bp,
        const float* __restrict__ query, const float* __restrict__ lng,
        const float* __restrict__ lnb, float* __restrict__ out, int M) {
    __shared__ __align__(16) __bf16 WH[128 * WPAD];
    __shared__ __align__(16) __bf16 WL[128 * WPAD];
    {
        const uint4* srcH = (const uint4*)wh;
        const uint4* srcL = (const uint4*)wl;
#pragma unroll
        for (int it = 0; it < 8; ++it) {
            int cid = threadIdx.x + it * 256;
            int n = cid >> 4, c16 = cid & 15;
            *(uint4*)((char*)WH + n * (WPAD * 2) + c16 * 16) = srcH[cid];
            *(uint4*)((char*)WL + n * (WPAD * 2) + c16 * 16) = srcL[cid];
        }
    }
    __syncthreads();

    int lane = threadIdx.x & 63;
    int wid  = threadIdx.x >> 6;
    int r = lane & 15, g = lane >> 4;
    int rb = blockIdx.x * 64 + wid * 16;

    int arow = rb + r; if (arow >= M) arow = M - 1;
    const float* xrow = msg + (size_t)arow * DIMN;
    bf16x8 Ah[4], Al[4];
#pragma unroll
    for (int ks = 0; ks < 4; ++ks) {
        const float* px = xrow + ks * 32 + g * 8;
        f32x4 v0 = *(const f32x4*)(px);
        f32x4 v1 = *(const f32x4*)(px + 4);
#pragma unroll
        for (int i = 0; i < 4; ++i) {
            __bf16 h0 = (__bf16)v0[i];
            __bf16 h1 = (__bf16)v1[i];
            Ah[ks][i]     = h0;
            Ah[ks][i + 4] = h1;
            Al[ks][i]     = (__bf16)(v0[i] - (float)h0);
            Al[ks][i + 4] = (__bf16)(v1[i] - (float)h1);
        }
    }
    float xv[8][4];
#pragma unroll
    for (int ct = 0; ct < 8; ++ct) {
        f32x4 acc = {0.f, 0.f, 0.f, 0.f};
        int n = ct * 16 + r;
#pragma unroll
        for (int ks = 0; ks < 4; ++ks) {
            bf16x8 Bh = *(const bf16x8*)(WH + n * WPAD + ks * 32 + g * 8);
            bf16x8 Bl = *(const bf16x8*)(WL + n * WPAD + ks * 32 + g * 8);
            acc = __builtin_amdgcn_mfma_f32_16x16x32_bf16(Ah[ks], Bh, acc, 0, 0, 0);
            acc = __builtin_amdgcn_mfma_f32_16x16x32_bf16(Ah[ks], Bl, acc, 0, 0, 0);
            acc = __builtin_amdgcn_mfma_f32_16x16x32_bf16(Al[ks], Bh, acc, 0, 0, 0);
        }
        float bn = bp[n];
#pragma unroll
        for (int i = 0; i < 4; ++i) {
            int row = rb + g * 4 + i;
            int rc = row < M ? row : M - 1;
            xv[ct][i] = acc[i] + bn + query[(size_t)rc * DIMN + n];
        }
    }
#pragma unroll
    for (int i = 0; i < 4; ++i) {
        float s = 0.f, ss = 0.f;
#pragma unroll
        for (int ct = 0; ct < 8; ++ct) { s += xv[ct][i]; ss += xv[ct][i] * xv[ct][i]; }
        s += __shfl_xor(s, 1, 64);  ss += __shfl_xor(ss, 1, 64);
        s += __shfl_xor(s, 2, 64);  ss += __shfl_xor(ss, 2, 64);
        s += __shfl_xor(s, 4, 64);  ss += __shfl_xor(ss, 4, 64);
        s += __shfl_xor(s, 8, 64);  ss += __shfl_xor(ss, 8, 64);
        float mean = s * (1.f / DIMN);
        float var  = ss * (1.f / DIMN) - mean * mean;
        float rstd = rsqrtf(var + LN_EPS);
        int row = rb + g * 4 + i;
#pragma unroll
        for (int ct = 0; ct < 8; ++ct) {
            int n = ct * 16 + r;
            if (row < M)
                out[(size_t)row * DIMN + n] = (xv[ct][i] - mean) * rstd * lng[n] + lnb[n];
        }
    }
}

extern "C" void kernel_launch(void* const* d_in, const int* in_sizes, int n_in,
                              void* d_out, int out_size, void* d_ws, size_t ws_size,
                              hipStream_t stream) {
    const float* query = (const float*)d_in[0];
    const float* keys  = (const float*)d_in[1];
    const float* values= (const float*)d_in[2];
    const int*   qidx  = (const int*)d_in[3];
    const int*   kidx  = (const int*)d_in[4];
    const float* Wq    = (const float*)d_in[5];
    const float* bq    = (const float*)d_in[6];
    const float* Wk    = (const float*)d_in[7];
    const float* bk    = (const float*)d_in[8];
    const float* Wv    = (const float*)d_in[9];
    const float* bv    = (const float*)d_in[10];
    const float* Wp    = (const float*)d_in[11];
    const float* bp    = (const float*)d_in[12];
    const float* a     = (const float*)d_in[13];
    const float* pw    = (const float*)d_in[14];
    const float* lng   = (const float*)d_in[15];
    const float* lnb   = (const float*)d_in[16];

    int NQ_ = in_sizes[0] / DIMN;
    int NK_ = in_sizes[1] / DIMN;
    int E_  = in_sizes[3];

    char* p = (char*)d_ws;
    __bf16* wsplit = (__bf16*)p;
    size_t off = (size_t)4 * 32768 * sizeof(__bf16);
    float*  Qp = (float*)(p + off);  off += (size_t)NQ_ * DIMN * 4;
    __bf16* KV = (__bf16*)(p + off); off += (size_t)NK_ * 256 * 2;
    int* counts = (int*)(p + off); off += (((size_t)NQ_ * 4) + 127) / 128 * 128;
    int* offs   = (int*)(p + off); off += (((size_t)NQ_ * 4) + 127) / 128 * 128;
    int* bsum   = (int*)(p + off); off += 1024 * 4;
    int* rank   = (int*)(p + off); off += (size_t)E_ * 4;
    int* skey   = (int*)(p + off); off += (size_t)E_ * 4;
    float* msg  = Qp;  // aliasing is safe: wave for query q reads only Qp row q

    hipMemsetAsync(counts, 0, (size_t)NQ_ * 4, stream);

    int ge = (E_ + 255) / 256;
    int gm = (NQ_ + 63) / 64;
    int nb = (NQ_ + 255) / 256;

    k_prep<<<256 + ge, 256, 0, stream>>>(Wq, Wk, Wv, Wp, wsplit, qidx, counts, rank, E_);

    int ntq = (NQ_ + 31) >> 5;
    int ntk = (NK_ + 31) >> 5;
    int total = ntq + 2 * ntk;
    int chunk = 5;                              // fine-grained: ~3.7 rounds, balanced
    int gproj = (total + chunk - 1) / chunk;
    if (gproj < nb) gproj = nb;                 // scan1 piggyback needs nb blocks
    k_proj3<<<gproj, 256, 0, stream>>>(query, keys, values, wsplit, bq, bk, bv,
                                       Qp, KV, NQ_, NK_, counts, offs, bsum, nb, chunk);

    k_scan2<<<1, 1024, 0, stream>>>(bsum, nb);

    k_scatter<<<ge, 256, 0, stream>>>(qidx, kidx, offs, bsum, rank, skey, E_);

    k_attn<<<(NQ_ + 3) / 4, 256, 0, stream>>>(Qp, KV, offs, bsum, skey, a, pw, msg, NQ_, E_);

    k_final<<<gm, 256, 0, stream>>>(msg, wsplit + 3 * 32768, wsplit + 3 * 32768 + 16384,
                                    bp, query, lng, lnb, (float*)d_out, NQ_);
}